// Round 1
// 290.646 us; speedup vs baseline: 1.0108x; 1.0108x over previous
//
#include <hip/hip_runtime.h>

#define RAYS 65536
#define NS   192

__device__ __forceinline__ int   f2i(float x){ return __builtin_bit_cast(int, x); }
__device__ __forceinline__ float i2f(int x)  { return __builtin_bit_cast(float, x); }

// v_mov_b32_dpp with old=0, bound_ctrl:0 (invalid lanes -> 0)
template<int CTRL, int ROWMASK>
__device__ __forceinline__ float dpp0(float x){
    return i2f(__builtin_amdgcn_update_dpp(0, f2i(x), CTRL, ROWMASK, 0xF, true));
}
template<int OFF>
__device__ __forceinline__ float swz(float x){
    return i2f(__builtin_amdgcn_ds_swizzle(f2i(x), OFF));
}

// partner value at sub-lane XOR distance JL (within each 32-lane half)
template<int JL>
__device__ __forceinline__ float partner(float x){
    if      constexpr (JL == 1) return dpp0<0xB1, 0xF>(x);   // quad_perm xor1
    else if constexpr (JL == 2) return dpp0<0x4E, 0xF>(x);   // quad_perm xor2
    else if constexpr (JL == 4) return swz<0x101F>(x);       // xor4
    else if constexpr (JL == 8) return swz<0x201F>(x);       // xor8
    else                        return swz<0x401F>(x);       // xor16
}

// ascending in-lane compare-exchange: 2 VALU (fmin+fmax), no selects
__device__ __forceinline__ void ce(float &a, float &b){
    float mn = fminf(a, b), mx = fmaxf(a, b);
    a = mn; b = mx;
}

// normalized (all-ascending) cross-lane phase at lane distance JL.
// 'lower' = ((sl & JL) == 0), hoisted to a lane mask once per kernel.
// keep own value iff (v < p) == lower; ties resolve consistently.
template<int JL>
__device__ __forceinline__ void xphase(float v[8], bool lower){
    #pragma unroll
    for (int r = 0; r < 8; ++r){
        float p = partner<JL>(v[r]);
        v[r] = ((v[r] < p) == lower) ? v[r] : p;
    }
}

// in-lane bitonic cleanup (strides 4,2,1), ascending
__device__ __forceinline__ void rmerge(float v[8]){
    ce(v[0],v[4]); ce(v[1],v[5]); ce(v[2],v[6]); ce(v[3],v[7]);
    ce(v[0],v[2]); ce(v[1],v[3]); ce(v[4],v[6]); ce(v[5],v[7]);
    ce(v[0],v[1]); ce(v[2],v[3]); ce(v[4],v[5]); ce(v[6],v[7]);
}

// flip sign bits of all 8 regs where mask (0 or 0x80000000)
__device__ __forceinline__ void flipsigns(float v[8], unsigned m){
    #pragma unroll
    for (int r = 0; r < 8; ++r) v[r] = i2f(f2i(v[r]) ^ (int)m);
}

// 32-lane butterfly sum (both halves independently)
__device__ __forceinline__ float halfsum(float a){
    a += dpp0<0xB1, 0xF>(a);
    a += dpp0<0x4E, 0xF>(a);
    a += swz<0x101F>(a);
    a += swz<0x201F>(a);
    a += swz<0x401F>(a);
    return a;
}

__global__ __launch_bounds__(256) void nerf_integrate(
    const float* __restrict__ t,
    const float* __restrict__ sigma,
    const float* __restrict__ c,
    float* __restrict__ out)
{
    const int tid  = threadIdx.x;
    const int lane = tid & 63;
    const int sl   = tid & 31;                     // sub-lane within the ray's 32 lanes
    const int ray  = blockIdx.x * 8 + (tid >> 5);  // 2 rays per wave, 8 per block

    const int b0 = sl & 1, b1 = (sl >> 1) & 1, b2 = (sl >> 2) & 1,
              b3 = (sl >> 3) & 1, b4 = (sl >> 4) & 1;
    // fixed lower-lane role masks for normalized cross phases
    const bool lo1  = (b0 == 0);
    const bool lo2  = (b1 == 0);
    const bool lo4  = (b2 == 0);
    const bool lo8  = (b3 == 0);
    const bool lo16 = (b4 == 0);

    // ---- load t: element e = 8*sl + r (193 real values, pad 1e30) ----
    const float* trow = t + (size_t)ray * 193;
    float v[8];
    if (sl < 24){
        #pragma unroll
        for (int r = 0; r < 8; ++r) v[r] = trow[8 * sl + r];
    } else if (sl == 24){
        v[0] = trow[192];
        #pragma unroll
        for (int r = 1; r < 8; ++r) v[r] = 1e30f;
    } else {
        #pragma unroll
        for (int r = 0; r < 8; ++r) v[r] = 1e30f;
    }

    // ==== sign-normalized bitonic sort of 256: index bits [2:0]=r, [7:3]=sl ====
    // storage sign s_i = -1 where stage direction is descending; all CEs ascend.

    // stage k<=8: per-lane full sort, direction = (b0==0) -> negate odd lanes
    flipsigns(v, (unsigned)b0 << 31);
    // Batcher odd-even 8-sorter, 19 CEs, ascending
    ce(v[0],v[1]); ce(v[2],v[3]); ce(v[4],v[5]); ce(v[6],v[7]);
    ce(v[0],v[2]); ce(v[1],v[3]); ce(v[4],v[6]); ce(v[5],v[7]);
    ce(v[1],v[2]); ce(v[5],v[6]);
    ce(v[0],v[4]); ce(v[1],v[5]); ce(v[2],v[6]); ce(v[3],v[7]);
    ce(v[2],v[4]); ce(v[3],v[5]);
    ce(v[1],v[2]); ce(v[3],v[4]); ce(v[5],v[6]);

    // k=16: direction bit b1
    flipsigns(v, (unsigned)(b0 ^ b1) << 31);
    xphase<1>(v, lo1);
    rmerge(v);
    // k=32: direction bit b2
    flipsigns(v, (unsigned)(b1 ^ b2) << 31);
    xphase<2>(v, lo2);
    xphase<1>(v, lo1);
    rmerge(v);
    // k=64: direction bit b3
    flipsigns(v, (unsigned)(b2 ^ b3) << 31);
    xphase<4>(v, lo4);
    xphase<2>(v, lo2);
    xphase<1>(v, lo1);
    rmerge(v);
    // k=128: direction bit b4
    flipsigns(v, (unsigned)(b3 ^ b4) << 31);
    xphase<8>(v, lo8);
    xphase<4>(v, lo4);
    xphase<2>(v, lo2);
    xphase<1>(v, lo1);
    rmerge(v);
    // k=256: ascending everywhere -> clear remaining negation
    flipsigns(v, (unsigned)b4 << 31);
    xphase<16>(v, lo16);
    xphase<8> (v, lo8);
    xphase<4> (v, lo4);
    xphase<2> (v, lo2);
    xphase<1> (v, lo1);
    rmerge(v);

    // ---- neighbor for r=7 (cross-lane before any divergence) ----
    float nxt = __shfl(v[0], lane + 1, 64);  // lane31/63 are pads -> don't care
    const bool act = (sl < 24);              // lane's 8 elements all < 192

    // ---- sigma, sdt ----
    float sg[8];
    if (act){
        const float* srow = sigma + (size_t)ray * NS + 8 * sl;
        float4 s0 = *reinterpret_cast<const float4*>(srow);
        float4 s1 = *reinterpret_cast<const float4*>(srow + 4);
        sg[0]=s0.x; sg[1]=s0.y; sg[2]=s0.z; sg[3]=s0.w;
        sg[4]=s1.x; sg[5]=s1.y; sg[6]=s1.z; sg[7]=s1.w;
    } else {
        #pragma unroll
        for (int r = 0; r < 8; ++r) sg[r] = 0.0f;
    }
    float sdt[8];
    #pragma unroll
    for (int r = 0; r < 8; ++r){
        float tn = (r < 7) ? v[r + 1] : nxt;
        sdt[r] = act ? sg[r] * (tn - v[r]) : 0.0f;
    }

    // ---- prefix sum: in-lane inclusive over 8, then per-half DPP scan ----
    float pre[8];
    float run = 0.0f;
    #pragma unroll
    for (int r = 0; r < 8; ++r){ run += sdt[r]; pre[r] = run; }
    float x = run;
    x += dpp0<0x111, 0xF>(x);   // row_shr:1
    x += dpp0<0x112, 0xF>(x);   // row_shr:2
    x += dpp0<0x114, 0xF>(x);   // row_shr:4
    x += dpp0<0x118, 0xF>(x);   // row_shr:8
    x += dpp0<0x142, 0xA>(x);   // row_bcast:15 into rows 1,3 (per-half scan)
    float laneExcl = x - run;

    // ---- wi via telescoped exponentials: excl_r == incl_{r-1} -> 9 exps ----
    float wi[8];
    float prev = __expf(-laneExcl);
    #pragma unroll
    for (int r = 0; r < 8; ++r){
        float e = __expf(-(laneExcl + pre[r]));
        wi[r] = prev - e;
        prev = e;
    }
    if (act){
        float* wrow = out + (size_t)RAYS * 3 + (size_t)ray * NS + 8 * sl;
        *reinterpret_cast<float4*>(wrow)     = make_float4(wi[0], wi[1], wi[2], wi[3]);
        *reinterpret_cast<float4*>(wrow + 4) = make_float4(wi[4], wi[5], wi[6], wi[7]);
    }

    // ---- rgb: load c, accumulate, per-half reduce ----
    float a0 = 0.f, a1 = 0.f, a2 = 0.f;
    if (act){
        const float* crow = c + (size_t)ray * (NS * 3) + 24 * sl;
        float cf[24];
        #pragma unroll
        for (int m = 0; m < 6; ++m){
            float4 cc = *reinterpret_cast<const float4*>(crow + 4 * m);
            cf[4*m+0]=cc.x; cf[4*m+1]=cc.y; cf[4*m+2]=cc.z; cf[4*m+3]=cc.w;
        }
        #pragma unroll
        for (int r = 0; r < 8; ++r){
            a0 += wi[r] * cf[3*r + 0];
            a1 += wi[r] * cf[3*r + 1];
            a2 += wi[r] * cf[3*r + 2];
        }
    }
    a0 = halfsum(a0);
    a1 = halfsum(a1);
    a2 = halfsum(a2);
    if (sl < 3){
        float val = (sl == 0) ? a0 : ((sl == 1) ? a1 : a2);
        out[(size_t)ray * 3 + sl] = val;
    }
}

extern "C" void kernel_launch(void* const* d_in, const int* in_sizes, int n_in,
                              void* d_out, int out_size, void* d_ws, size_t ws_size,
                              hipStream_t stream) {
    const float* t     = (const float*)d_in[0];
    const float* sigma = (const float*)d_in[1];
    const float* c     = (const float*)d_in[2];
    float* out = (float*)d_out;
    nerf_integrate<<<RAYS / 8, 256, 0, stream>>>(t, sigma, c, out);
}